// Round 1
// baseline (354.539 us; speedup 1.0000x reference)
//
#include <hip/hip_runtime.h>
#include <cstddef>

#define PI_F 3.14159265358979323846f
#define A_  5
#define C_  12
#define RPG (C_ * A_)    // (coil,a) rows = 60

// ---------------------------------------------------------------------------
// Device-global scratch. Layouts:
//   g_bufA after k_fft1c  : [ca][ym(256)][kx(512)]  (ym = padded y - 128)
//   g_bufB after k_transA : [ca][kx(512)][ym(256)]
//   g_bufB after k_colfmc : [ca][kx(512)][ym(256)]  (fused fft/mix/ifft, in place)
//   g_bufA after k_transB : [ca][ym(256)][kx(512)]
//   g_bufB after k_outifft: [ca][h(256)][w(256)]
// ca = coil*A_ + a.  (g_bufC eliminated: spectra never touch HBM.)
// ---------------------------------------------------------------------------
__device__ float2 g_bufA[RPG * 256 * 512];  //  63 MB
__device__ float2 g_bufB[RPG * 512 * 256];  //  63 MB
__device__ float2 g_kernT[25 * 512 * 512];  // 52.4 MB, transposed + pre-scaled

// ---------------------------------------------------------------------------
// SoA LDS FFT, index padding, radix-4 (R13-proven: bank conflicts 6.5M -> 0).
// ---------------------------------------------------------------------------
#define NP 528
__device__ inline int PADI(int i) { return i + (i >> 5); }

__device__ inline void build_tab512(float2* tab, int t) {
    #pragma unroll
    for (int q = 0; q < 4; ++q) {
        int k = t + q * 128;
        float s, c;
        __sincosf(-2.0f * PI_F * (float)k * (1.0f / 512.0f), &s, &c);
        tab[k] = make_float2(c, s);
    }
}

template<int DIR>
__device__ inline float2 cmulw(float2 v, float2 w) {
    float cv = w.x, sv = (DIR < 0) ? w.y : -w.y;   // DIR=+1 -> conj(w)
    return make_float2(v.x * cv - v.y * sv, v.x * sv + v.y * cv);
}

// 512-pt FFT: 4 radix-4 stages + 1 radix-2 stage, 128 threads.
template<int DIR>
__device__ void fft512_r4(float*& sre, float*& sim, float* dre, float* dim,
                          const float2* tab, int t) {
    float *srcR = sre, *srcI = sim, *dstR = dre, *dstI = dim;
    int Ns = 1;
    #pragma unroll
    for (int s = 0; s < 4; ++s) {
        __syncthreads();
        int j = t;
        int m = j & (Ns - 1);
        int e1 = m << (7 - 2 * s);
        float2 w1 = tab[e1], w2 = tab[2 * e1], w3 = tab[3 * e1];
        int i0 = PADI(j), i1 = PADI(j + 128), i2 = PADI(j + 256), i3 = PADI(j + 384);
        float2 v0 = make_float2(srcR[i0], srcI[i0]);
        float2 v1 = cmulw<DIR>(make_float2(srcR[i1], srcI[i1]), w1);
        float2 v2 = cmulw<DIR>(make_float2(srcR[i2], srcI[i2]), w2);
        float2 v3 = cmulw<DIR>(make_float2(srcR[i3], srcI[i3]), w3);
        float2 t0 = make_float2(v0.x + v2.x, v0.y + v2.y);
        float2 t1 = make_float2(v0.x - v2.x, v0.y - v2.y);
        float2 t2 = make_float2(v1.x + v3.x, v1.y + v3.y);
        float2 t3 = make_float2(v1.x - v3.x, v1.y - v3.y);
        float2 y0 = make_float2(t0.x + t2.x, t0.y + t2.y);
        float2 y2 = make_float2(t0.x - t2.x, t0.y - t2.y);
        float2 y1, y3;
        if (DIR < 0) {
            y1 = make_float2(t1.x + t3.y, t1.y - t3.x);
            y3 = make_float2(t1.x - t3.y, t1.y + t3.x);
        } else {
            y1 = make_float2(t1.x - t3.y, t1.y + t3.x);
            y3 = make_float2(t1.x + t3.y, t1.y - t3.x);
        }
        int idxD = ((j & ~(Ns - 1)) << 2) | m;
        int o0 = PADI(idxD), o1 = PADI(idxD + Ns);
        int o2 = PADI(idxD + 2 * Ns), o3 = PADI(idxD + 3 * Ns);
        dstR[o0] = y0.x; dstI[o0] = y0.y;
        dstR[o1] = y1.x; dstI[o1] = y1.y;
        dstR[o2] = y2.x; dstI[o2] = y2.y;
        dstR[o3] = y3.x; dstI[o3] = y3.y;
        float* tr = srcR; srcR = dstR; dstR = tr;
        float* ti = srcI; srcI = dstI; dstI = ti;
        Ns <<= 2;
    }
    __syncthreads();
    #pragma unroll
    for (int q = 0; q < 2; ++q) {
        int j = t + q * 128;
        float2 w = tab[j];
        int i0 = PADI(j), i1 = PADI(j + 256);
        float2 v0 = make_float2(srcR[i0], srcI[i0]);
        float2 tw = cmulw<DIR>(make_float2(srcR[i1], srcI[i1]), w);
        dstR[i0] = v0.x + tw.x; dstI[i0] = v0.y + tw.y;
        dstR[i1] = v0.x - tw.x; dstI[i1] = v0.y - tw.y;
    }
    __syncthreads();
    sre = dstR; sim = dstI;
}

// ---------------------------------------------------------------------------
// Transposed, pre-scaled kernel cache: g_kernT[m][kx][ky] = kern[m][ky][kx]*s.
// ---------------------------------------------------------------------------
__global__ void k_kernT2(const float* __restrict__ kr, const float* __restrict__ ki,
                         float scale) {
    __shared__ float tR[32][33], tI[32][33];
    int m = blockIdx.z;
    size_t base = (size_t)m << 18;
    int c0 = blockIdx.x * 32;
    int r0 = blockIdx.y * 32;
    int tx = threadIdx.x, ty = threadIdx.y;
    for (int i = ty; i < 32; i += 8) {
        size_t idx = base + (size_t)(c0 + i) * 512 + (r0 + tx);
        tR[i][tx] = kr[idx] * scale;
        tI[i][tx] = ki[idx] * scale;
    }
    __syncthreads();
    for (int i = ty; i < 32; i += 8)
        g_kernT[base + (size_t)(r0 + i) * 512 + (c0 + tx)] =
            make_float2(tR[tx][i], tI[tx][i]);
}

// ---------------------------------------------------------------------------
// Pad x + modulate mps_c*x + row FFT along x, banded store. Block = ca*256+ym.
// ---------------------------------------------------------------------------
__global__ void k_fft1c(const float* __restrict__ xr, const float* __restrict__ xi,
                        const float* __restrict__ mr, const float* __restrict__ mi) {
    int row = blockIdx.x;
    int ca = row >> 8;
    int ym = row & 255;
    int coil = ca / A_;
    int a = ca - coil * A_;
    int t = threadIdx.x;
    __shared__ float reA[NP], imA[NP], reB[NP], imB[NP];
    __shared__ float2 tab[512];
    build_tab512(tab, t);
    size_t xBase = ((size_t)a * 256 + ym) * 256;
    size_t mBase = ((size_t)coil * 256 + ym) * 256;
    #pragma unroll
    for (int q = 0; q < 4; ++q) {
        int x5 = t + q * 128;
        float vr = 0.f, vi = 0.f;
        if (x5 >= 128 && x5 < 384) {
            int xm = x5 - 128;
            float ar = xr[xBase + xm], ai = xi[xBase + xm];
            float br = mr[mBase + xm], bi = mi[mBase + xm];
            vr = ar * br - ai * bi;
            vi = ar * bi + ai * br;
        }
        int p = PADI(x5);
        reA[p] = vr; imA[p] = vi;
    }
    float *sre = reA, *sim = imA;
    fft512_r4<-1>(sre, sim, reB, imB, tab, t);
    float2* o = g_bufA + (size_t)row * 512;
    #pragma unroll
    for (int q = 0; q < 4; ++q) {
        int k = t + q * 128;
        int p = PADI(k);
        o[k] = make_float2(sre[p], sim[p]);
    }
}

// ---------------------------------------------------------------------------
// transA: per-ca transpose (256 ym x 512 kx) -> (512 kx x 256 ym). SoA tile.
// ---------------------------------------------------------------------------
__global__ void k_transA() {
    __shared__ float tR[32][33], tI[32][33];
    int ca = blockIdx.z;
    const float2* sIn = g_bufA + (size_t)ca * (256 * 512);
    float2* sOut = g_bufB + (size_t)ca * (512 * 256);
    int kx0 = blockIdx.x * 32, ym0 = blockIdx.y * 32;
    int tx = threadIdx.x, ty = threadIdx.y;
    for (int i = ty; i < 32; i += 8) {
        float2 v = sIn[(size_t)(ym0 + i) * 512 + kx0 + tx];
        tR[i][tx] = v.x; tI[i][tx] = v.y;
    }
    __syncthreads();
    for (int i = ty; i < 32; i += 8)
        sOut[(size_t)(kx0 + i) * 256 + ym0 + tx] =
            make_float2(tR[tx][i], tI[tx][i]);
}

// ---------------------------------------------------------------------------
// FUSED column pass: per (coil,kx) block, the 5 ain forward FFTs, the
// pointwise k-space mix, and the 5 aout inverse FFTs -- spectra live
// entirely in LDS (FR/FI), never in HBM. This deletes bufC and its
// ~500 MB round-trip (colfft write + mix read/write + colifft read).
//   - mix is per-coil independent: G[aout] = sum_ain K[aout,ain]*F[ain]
//   - per-thread ky ownership {t, t+128, t+256, t+384} is disjoint and
//     consistent across phases -> in-place mix needs no barrier
//   - output written in place to bufB: the block reads all 5 input
//     columns before writing the same 5 slots; no other block touches them
//   - K rows (102 KB per kx) reused by the 12 coil-blocks of a kx
//     (coil = blockIdx.x, fast-varying) -> served from L2/L3
// LDS = 8.4K workspace + 4K tab + 20.5K F = 33 KB -> 4 blocks/CU.
// ---------------------------------------------------------------------------
__global__ void __launch_bounds__(128) k_colfmc() {
    int coil = blockIdx.x;           // 0..11
    int kx   = blockIdx.y;           // 0..511
    int t = threadIdx.x;
    __shared__ float reA[NP], imA[NP], reB[NP], imB[NP];
    __shared__ float FR[A_][512], FI[A_][512];
    __shared__ float2 tab[512];
    build_tab512(tab, t);

    // ---- forward: 5 ain column FFTs with pad-on-load ----
    for (int ain = 0; ain < A_; ++ain) {
        const float4* g4 = (const float4*)(g_bufB +
            ((size_t)(coil * A_ + ain) * 512 + kx) * 256);
        float4 v = g4[t];            // elements 2t,2t+1 -> y = 128+2t, 129+2t
        int y0 = 128 + 2 * t;
        int p0 = PADI(y0), p1 = PADI(y0 + 1);
        reA[p0] = v.x; imA[p0] = v.y;
        reA[p1] = v.z; imA[p1] = v.w;
        int q0 = PADI(t), q1 = PADI(t + 384);   // zero pads y<128, y>=384
        reA[q0] = 0.f; imA[q0] = 0.f;
        reA[q1] = 0.f; imA[q1] = 0.f;
        float *sre = reA, *sim = imA;
        fft512_r4<-1>(sre, sim, reB, imB, tab, t);   // ends with barrier
        #pragma unroll
        for (int q = 0; q < 4; ++q) {
            int k = t + q * 128;
            int p = PADI(k);
            FR[ain][k] = sre[p];
            FI[ain][k] = sim[p];
        }
        // next iteration's reA writes are own-thread slots; fft's leading
        // barrier orders the FR copies vs. the next stage-0 writes to reB
    }
    __syncthreads();                 // FR/FI complete for all ain

    // ---- pointwise mix, in place over FR/FI ----
    size_t kBase = (size_t)kx << 9;
    #pragma unroll
    for (int q = 0; q < 4; ++q) {
        int ky = t + q * 128;
        float fr[A_], fi[A_];
        #pragma unroll
        for (int ain = 0; ain < A_; ++ain) {
            fr[ain] = FR[ain][ky];
            fi[ain] = FI[ain][ky];
        }
        #pragma unroll
        for (int aout = 0; aout < A_; ++aout) {
            float gr = 0.f, gi = 0.f;
            #pragma unroll
            for (int ain = 0; ain < A_; ++ain) {
                float2 k = g_kernT[((size_t)(aout * A_ + ain) << 18) + kBase + ky];
                gr += k.x * fr[ain] - k.y * fi[ain];
                gi += k.x * fi[ain] + k.y * fr[ain];
            }
            FR[aout][ky] = gr; FI[aout][ky] = gi;
        }
    }
    // no barrier: each thread re-reads only its own ky slots below

    // ---- inverse: 5 aout column IFFTs, crop y, in-place store to bufB ----
    for (int aout = 0; aout < A_; ++aout) {
        #pragma unroll
        for (int q = 0; q < 4; ++q) {
            int k = t + q * 128;
            int p = PADI(k);
            reA[p] = FR[aout][k];
            imA[p] = FI[aout][k];
        }
        float *sre = reA, *sim = imA;
        fft512_r4<1>(sre, sim, reB, imB, tab, t);
        float4* o4 = (float4*)(g_bufB +
            ((size_t)(coil * A_ + aout) * 512 + kx) * 256);
        int y0 = 128 + 2 * t;        // keep y in [128,384)
        int p0 = PADI(y0), p1 = PADI(y0 + 1);
        o4[t] = make_float4(sre[p0], sim[p0], sre[p1], sim[p1]);
    }
}

// ---------------------------------------------------------------------------
// transB: per-ca transpose (512 kx x 256 ym) -> (256 ym x 512 kx).
// Now reads bufB (fused kernel's in-place output), writes bufA.
// ---------------------------------------------------------------------------
__global__ void k_transB() {
    __shared__ float tR[32][33], tI[32][33];
    int ca = blockIdx.z;
    const float2* sIn = g_bufB + (size_t)ca * (512 * 256);
    float2* sOut = g_bufA + (size_t)ca * (256 * 512);
    int ym0 = blockIdx.x * 32, kx0 = blockIdx.y * 32;
    int tx = threadIdx.x, ty = threadIdx.y;
    for (int i = ty; i < 32; i += 8) {
        float2 v = sIn[(size_t)(kx0 + i) * 256 + ym0 + tx];
        tR[i][tx] = v.x; tI[i][tx] = v.y;
    }
    __syncthreads();
    for (int i = ty; i < 32; i += 8)
        sOut[(size_t)(ym0 + i) * 512 + kx0 + tx] =
            make_float2(tR[tx][i], tI[tx][i]);
}

// ---------------------------------------------------------------------------
// Row IFFT along kx + crop x. Reads bufA, banded store to bufB [ca][h][w].
// ---------------------------------------------------------------------------
__global__ void k_outifft() {
    int row = blockIdx.x;            // ca*256 + h
    int t = threadIdx.x;
    __shared__ float reA[NP], imA[NP], reB[NP], imB[NP];
    __shared__ float2 tab[512];
    build_tab512(tab, t);
    const float4* s4 = (const float4*)(g_bufA + (size_t)row * 512);
    #pragma unroll
    for (int q = 0; q < 2; ++q) {
        int e = t + q * 128;
        float4 v = s4[e];
        int p0 = PADI(2 * e), p1 = PADI(2 * e + 1);
        reA[p0] = v.x; imA[p0] = v.y;
        reA[p1] = v.z; imA[p1] = v.w;
    }
    float *sre = reA, *sim = imA;
    fft512_r4<1>(sre, sim, reB, imB, tab, t);
    float4* o4 = (float4*)(g_bufB + (size_t)row * 256);
    int w0 = 128 + 2 * t;            // crop x: keep [128,384)
    int p0 = PADI(w0), p1 = PADI(w0 + 1);
    o4[t] = make_float4(sre[p0], sim[p0], sre[p1], sim[p1]);
}

// ---------------------------------------------------------------------------
// Coil reduction: out[a,h,w] = sum_c conj(mps[c,h,w]) * v[c,a,h,w].
// Reads bufB [ca][h][w]. Planar out: Re plane then Im plane.
// ---------------------------------------------------------------------------
__global__ void k_outred(const float* __restrict__ mr, const float* __restrict__ mi,
                         float* __restrict__ out, int outFloats) {
    int row = blockIdx.x;            // a*256 + h
    int a = row >> 8;
    int h = row & 255;
    int w = threadIdx.x;             // 0..255
    float ar = 0.f, ai = 0.f;
    #pragma unroll
    for (int c = 0; c < C_; ++c) {
        float2 v = g_bufB[(((size_t)(c * A_ + a) * 256 + h)) * 256 + w];
        size_t mIdx = ((size_t)c * 256 + h) * 256 + w;
        float br = mr[mIdx], bi = -mi[mIdx];   // conj(mps)
        ar += v.x * br - v.y * bi;
        ai += v.x * bi + v.y * br;
    }
    size_t p = ((size_t)a * 256 + h) * 256 + w;
    size_t reIdx = p, imIdx = 327680 + p;
    if (reIdx < (size_t)outFloats) out[reIdx] = ar;
    if (imIdx < (size_t)outFloats) out[imIdx] = ai;
}

// ---------------------------------------------------------------------------
extern "C" void kernel_launch(void* const* d_in, const int* in_sizes, int n_in,
                              void* d_out, int out_size, void* d_ws, size_t ws_size,
                              hipStream_t stream) {
    const float* xr = (const float*)d_in[0];
    const float* xi = (const float*)d_in[1];
    const float* mr = (const float*)d_in[2];
    const float* mi = (const float*)d_in[3];
    const float* kr = (const float*)d_in[4];
    const float* ki = (const float*)d_in[5];
    float* out = (float*)d_out;
    (void)d_ws; (void)ws_size; (void)n_in; (void)in_sizes;

    const float scale = 4.0f / 262144.0f;   // OVERSAMP^2/(Hp*Wp), ortho norms

    k_kernT2 <<<dim3(16, 16, 25), dim3(32, 8), 0, stream>>>(kr, ki, scale);
    k_fft1c  <<<RPG * 256, 128, 0, stream>>>(xr, xi, mr, mi);
    k_transA <<<dim3(16, 8, RPG), dim3(32, 8), 0, stream>>>();
    k_colfmc <<<dim3(C_, 512), 128, 0, stream>>>();
    k_transB <<<dim3(8, 16, RPG), dim3(32, 8), 0, stream>>>();
    k_outifft<<<RPG * 256, 128, 0, stream>>>();
    k_outred <<<A_ * 256, 256, 0, stream>>>(mr, mi, out, out_size);
}

// Round 2
// 332.505 us; speedup vs baseline: 1.0663x; 1.0663x over previous
//
#include <hip/hip_runtime.h>
#include <cstddef>

#define PI_F 3.14159265358979323846f
#define A_  5
#define C_  12
#define RPG (C_ * A_)    // (coil,a) rows = 60

// ---------------------------------------------------------------------------
// Device-global scratch. Layouts:
//   g_bufA after k_fft1c  : [ca][ym(256)][kx(512)]  (ym = padded y - 128)
//   g_bufB after k_transA : [ca][kx(512)][ym(256)]
//   g_bufB after k_colfmc : [ca][kx(512)][ym(256)]  (fused fft/mix/ifft, in place)
//   g_bufA after k_transB : [ca][ym(256)][kx(512)]
//   g_bufB after k_outifft: [ca][h(256)][w(256)]
// ca = coil*A_ + a.  (spectra never touch HBM.)
// ---------------------------------------------------------------------------
__device__ float2 g_bufA[RPG * 256 * 512];  //  63 MB
__device__ float2 g_bufB[RPG * 512 * 256];  //  63 MB
__device__ float2 g_kernT[25 * 512 * 512];  // 52.4 MB, transposed + pre-scaled

// ---------------------------------------------------------------------------
// SoA LDS FFT, index padding, radix-4 (R13-proven: bank conflicts 6.5M -> 0).
// Twiddle table is 256 entries (2 KB): radix-4 stages need e1 < 128 and
// 2*e1 < 256; w3 = w1*w2 computed in-register; final radix-2 needs j < 256.
// This keeps k_colfmc LDS below 32 KB -> 5 blocks/CU instead of 4.
// ---------------------------------------------------------------------------
#define NP 528
__device__ inline int PADI(int i) { return i + (i >> 5); }

__device__ inline void build_tab256(float2* tab, int t) {
    #pragma unroll
    for (int q = 0; q < 2; ++q) {
        int k = t + q * 128;
        float s, c;
        __sincosf(-2.0f * PI_F * (float)k * (1.0f / 512.0f), &s, &c);
        tab[k] = make_float2(c, s);
    }
}

template<int DIR>
__device__ inline float2 cmulw(float2 v, float2 w) {
    float cv = w.x, sv = (DIR < 0) ? w.y : -w.y;   // DIR=+1 -> conj(w)
    return make_float2(v.x * cv - v.y * sv, v.x * sv + v.y * cv);
}

// 512-pt FFT: 4 radix-4 stages + 1 radix-2 stage, 128 threads.
template<int DIR>
__device__ void fft512_r4(float*& sre, float*& sim, float* dre, float* dim,
                          const float2* tab, int t) {
    float *srcR = sre, *srcI = sim, *dstR = dre, *dstI = dim;
    int Ns = 1;
    #pragma unroll
    for (int s = 0; s < 4; ++s) {
        __syncthreads();
        int j = t;
        int m = j & (Ns - 1);
        int e1 = m << (7 - 2 * s);            // e1 in [0,128)
        float2 w1 = tab[e1], w2 = tab[2 * e1];
        float2 w3 = make_float2(w1.x * w2.x - w1.y * w2.y,
                                w1.x * w2.y + w1.y * w2.x);   // W^(3*e1)
        int i0 = PADI(j), i1 = PADI(j + 128), i2 = PADI(j + 256), i3 = PADI(j + 384);
        float2 v0 = make_float2(srcR[i0], srcI[i0]);
        float2 v1 = cmulw<DIR>(make_float2(srcR[i1], srcI[i1]), w1);
        float2 v2 = cmulw<DIR>(make_float2(srcR[i2], srcI[i2]), w2);
        float2 v3 = cmulw<DIR>(make_float2(srcR[i3], srcI[i3]), w3);
        float2 t0 = make_float2(v0.x + v2.x, v0.y + v2.y);
        float2 t1 = make_float2(v0.x - v2.x, v0.y - v2.y);
        float2 t2 = make_float2(v1.x + v3.x, v1.y + v3.y);
        float2 t3 = make_float2(v1.x - v3.x, v1.y - v3.y);
        float2 y0 = make_float2(t0.x + t2.x, t0.y + t2.y);
        float2 y2 = make_float2(t0.x - t2.x, t0.y - t2.y);
        float2 y1, y3;
        if (DIR < 0) {
            y1 = make_float2(t1.x + t3.y, t1.y - t3.x);
            y3 = make_float2(t1.x - t3.y, t1.y + t3.x);
        } else {
            y1 = make_float2(t1.x - t3.y, t1.y + t3.x);
            y3 = make_float2(t1.x + t3.y, t1.y - t3.x);
        }
        int idxD = ((j & ~(Ns - 1)) << 2) | m;
        int o0 = PADI(idxD), o1 = PADI(idxD + Ns);
        int o2 = PADI(idxD + 2 * Ns), o3 = PADI(idxD + 3 * Ns);
        dstR[o0] = y0.x; dstI[o0] = y0.y;
        dstR[o1] = y1.x; dstI[o1] = y1.y;
        dstR[o2] = y2.x; dstI[o2] = y2.y;
        dstR[o3] = y3.x; dstI[o3] = y3.y;
        float* tr = srcR; srcR = dstR; dstR = tr;
        float* ti = srcI; srcI = dstI; dstI = ti;
        Ns <<= 2;
    }
    __syncthreads();
    #pragma unroll
    for (int q = 0; q < 2; ++q) {
        int j = t + q * 128;                  // j in [0,256)
        float2 w = tab[j];
        int i0 = PADI(j), i1 = PADI(j + 256);
        float2 v0 = make_float2(srcR[i0], srcI[i0]);
        float2 tw = cmulw<DIR>(make_float2(srcR[i1], srcI[i1]), w);
        dstR[i0] = v0.x + tw.x; dstI[i0] = v0.y + tw.y;
        dstR[i1] = v0.x - tw.x; dstI[i1] = v0.y - tw.y;
    }
    __syncthreads();
    sre = dstR; sim = dstI;
}

// ---------------------------------------------------------------------------
// Transposed, pre-scaled kernel cache: g_kernT[m][kx][ky] = kern[m][ky][kx]*s.
// ---------------------------------------------------------------------------
__global__ void k_kernT2(const float* __restrict__ kr, const float* __restrict__ ki,
                         float scale) {
    __shared__ float tR[32][33], tI[32][33];
    int m = blockIdx.z;
    size_t base = (size_t)m << 18;
    int c0 = blockIdx.x * 32;
    int r0 = blockIdx.y * 32;
    int tx = threadIdx.x, ty = threadIdx.y;
    for (int i = ty; i < 32; i += 8) {
        size_t idx = base + (size_t)(c0 + i) * 512 + (r0 + tx);
        tR[i][tx] = kr[idx] * scale;
        tI[i][tx] = ki[idx] * scale;
    }
    __syncthreads();
    for (int i = ty; i < 32; i += 8)
        g_kernT[base + (size_t)(r0 + i) * 512 + (c0 + tx)] =
            make_float2(tR[tx][i], tI[tx][i]);
}

// ---------------------------------------------------------------------------
// Pad x + modulate mps_c*x + row FFT along x, banded store. Block = ca*256+ym.
// ---------------------------------------------------------------------------
__global__ void k_fft1c(const float* __restrict__ xr, const float* __restrict__ xi,
                        const float* __restrict__ mr, const float* __restrict__ mi) {
    int row = blockIdx.x;
    int ca = row >> 8;
    int ym = row & 255;
    int coil = ca / A_;
    int a = ca - coil * A_;
    int t = threadIdx.x;
    __shared__ float reA[NP], imA[NP], reB[NP], imB[NP];
    __shared__ float2 tab[256];
    build_tab256(tab, t);
    size_t xBase = ((size_t)a * 256 + ym) * 256;
    size_t mBase = ((size_t)coil * 256 + ym) * 256;
    #pragma unroll
    for (int q = 0; q < 4; ++q) {
        int x5 = t + q * 128;
        float vr = 0.f, vi = 0.f;
        if (x5 >= 128 && x5 < 384) {
            int xm = x5 - 128;
            float ar = xr[xBase + xm], ai = xi[xBase + xm];
            float br = mr[mBase + xm], bi = mi[mBase + xm];
            vr = ar * br - ai * bi;
            vi = ar * bi + ai * br;
        }
        int p = PADI(x5);
        reA[p] = vr; imA[p] = vi;
    }
    float *sre = reA, *sim = imA;
    fft512_r4<-1>(sre, sim, reB, imB, tab, t);
    float2* o = g_bufA + (size_t)row * 512;
    #pragma unroll
    for (int q = 0; q < 4; ++q) {
        int k = t + q * 128;
        int p = PADI(k);
        o[k] = make_float2(sre[p], sim[p]);
    }
}

// ---------------------------------------------------------------------------
// transA: per-ca transpose (256 ym x 512 kx) -> (512 kx x 256 ym). SoA tile.
// ---------------------------------------------------------------------------
__global__ void k_transA() {
    __shared__ float tR[32][33], tI[32][33];
    int ca = blockIdx.z;
    const float2* sIn = g_bufA + (size_t)ca * (256 * 512);
    float2* sOut = g_bufB + (size_t)ca * (512 * 256);
    int kx0 = blockIdx.x * 32, ym0 = blockIdx.y * 32;
    int tx = threadIdx.x, ty = threadIdx.y;
    for (int i = ty; i < 32; i += 8) {
        float2 v = sIn[(size_t)(ym0 + i) * 512 + kx0 + tx];
        tR[i][tx] = v.x; tI[i][tx] = v.y;
    }
    __syncthreads();
    for (int i = ty; i < 32; i += 8)
        sOut[(size_t)(kx0 + i) * 256 + ym0 + tx] =
            make_float2(tR[tx][i], tI[tx][i]);
}

// ---------------------------------------------------------------------------
// FUSED column pass: per (coil,kx) block, the 5 ain forward FFTs, the
// pointwise k-space mix, and the 5 aout inverse FFTs -- spectra live
// entirely in LDS (FR/FI), never in HBM.
//
// R1 counters: FETCH 240 MB (K re-fetched ~3.4x: the 12 coil-blocks of a kx
// were round-robined across 8 XCDs whose L2s don't share), Occ 19.9%
// (LDS 33.3 KB -> 4 blocks/CU). Fixes:
//   (a) XCD-clustered bijective swizzle: block b -> xcd = b&7 owns
//       kx = (b&7) + 8*((b>>3)/12), coil = (b>>3)%12. All 12 coil-blocks of
//       a kx land on ONE XCD within a 96-id launch window -> K row (102 KB)
//       stays in that XCD's L2 across its 12 uses (~1.3 MB in-flight K
//       working set per XCD).
//   (b) tab shrunk to 256 entries -> LDS 30,976 B -> 5 blocks/CU.
// ---------------------------------------------------------------------------
__global__ void __launch_bounds__(128) k_colfmc() {
    int b = blockIdx.x;              // 0..6143
    int j = b >> 3;                  // 0..767
    int kx   = (b & 7) + ((j / C_) << 3);   // 0..511, xcd-clustered
    int coil = j % C_;               // 0..11
    int t = threadIdx.x;
    __shared__ float reA[NP], imA[NP], reB[NP], imB[NP];
    __shared__ float FR[A_][512], FI[A_][512];
    __shared__ float2 tab[256];
    build_tab256(tab, t);

    // ---- forward: 5 ain column FFTs with pad-on-load ----
    for (int ain = 0; ain < A_; ++ain) {
        const float4* g4 = (const float4*)(g_bufB +
            ((size_t)(coil * A_ + ain) * 512 + kx) * 256);
        float4 v = g4[t];            // elements 2t,2t+1 -> y = 128+2t, 129+2t
        int y0 = 128 + 2 * t;
        int p0 = PADI(y0), p1 = PADI(y0 + 1);
        reA[p0] = v.x; imA[p0] = v.y;
        reA[p1] = v.z; imA[p1] = v.w;
        int q0 = PADI(t), q1 = PADI(t + 384);   // zero pads y<128, y>=384
        reA[q0] = 0.f; imA[q0] = 0.f;
        reA[q1] = 0.f; imA[q1] = 0.f;
        float *sre = reA, *sim = imA;
        fft512_r4<-1>(sre, sim, reB, imB, tab, t);   // ends with barrier
        #pragma unroll
        for (int q = 0; q < 4; ++q) {
            int k = t + q * 128;
            int p = PADI(k);
            FR[ain][k] = sre[p];
            FI[ain][k] = sim[p];
        }
    }
    __syncthreads();                 // FR/FI complete for all ain

    // ---- pointwise mix, in place over FR/FI ----
    size_t kBase = (size_t)kx << 9;
    #pragma unroll
    for (int q = 0; q < 4; ++q) {
        int ky = t + q * 128;
        float fr[A_], fi[A_];
        #pragma unroll
        for (int ain = 0; ain < A_; ++ain) {
            fr[ain] = FR[ain][ky];
            fi[ain] = FI[ain][ky];
        }
        #pragma unroll
        for (int aout = 0; aout < A_; ++aout) {
            float gr = 0.f, gi = 0.f;
            #pragma unroll
            for (int ain = 0; ain < A_; ++ain) {
                float2 k = g_kernT[((size_t)(aout * A_ + ain) << 18) + kBase + ky];
                gr += k.x * fr[ain] - k.y * fi[ain];
                gi += k.x * fi[ain] + k.y * fr[ain];
            }
            FR[aout][ky] = gr; FI[aout][ky] = gi;
        }
    }
    // no barrier: each thread re-reads only its own ky slots below

    // ---- inverse: 5 aout column IFFTs, crop y, in-place store to bufB ----
    for (int aout = 0; aout < A_; ++aout) {
        #pragma unroll
        for (int q = 0; q < 4; ++q) {
            int k = t + q * 128;
            int p = PADI(k);
            reA[p] = FR[aout][k];
            imA[p] = FI[aout][k];
        }
        float *sre = reA, *sim = imA;
        fft512_r4<1>(sre, sim, reB, imB, tab, t);
        float4* o4 = (float4*)(g_bufB +
            ((size_t)(coil * A_ + aout) * 512 + kx) * 256);
        int y0 = 128 + 2 * t;        // keep y in [128,384)
        int p0 = PADI(y0), p1 = PADI(y0 + 1);
        o4[t] = make_float4(sre[p0], sim[p0], sre[p1], sim[p1]);
    }
}

// ---------------------------------------------------------------------------
// transB: per-ca transpose (512 kx x 256 ym) -> (256 ym x 512 kx).
// Reads bufB (fused kernel's in-place output), writes bufA.
// ---------------------------------------------------------------------------
__global__ void k_transB() {
    __shared__ float tR[32][33], tI[32][33];
    int ca = blockIdx.z;
    const float2* sIn = g_bufB + (size_t)ca * (512 * 256);
    float2* sOut = g_bufA + (size_t)ca * (256 * 512);
    int ym0 = blockIdx.x * 32, kx0 = blockIdx.y * 32;
    int tx = threadIdx.x, ty = threadIdx.y;
    for (int i = ty; i < 32; i += 8) {
        float2 v = sIn[(size_t)(kx0 + i) * 256 + ym0 + tx];
        tR[i][tx] = v.x; tI[i][tx] = v.y;
    }
    __syncthreads();
    for (int i = ty; i < 32; i += 8)
        sOut[(size_t)(ym0 + i) * 512 + kx0 + tx] =
            make_float2(tR[tx][i], tI[tx][i]);
}

// ---------------------------------------------------------------------------
// Row IFFT along kx + crop x. Reads bufA, banded store to bufB [ca][h][w].
// ---------------------------------------------------------------------------
__global__ void k_outifft() {
    int row = blockIdx.x;            // ca*256 + h
    int t = threadIdx.x;
    __shared__ float reA[NP], imA[NP], reB[NP], imB[NP];
    __shared__ float2 tab[256];
    build_tab256(tab, t);
    const float4* s4 = (const float4*)(g_bufA + (size_t)row * 512);
    #pragma unroll
    for (int q = 0; q < 2; ++q) {
        int e = t + q * 128;
        float4 v = s4[e];
        int p0 = PADI(2 * e), p1 = PADI(2 * e + 1);
        reA[p0] = v.x; imA[p0] = v.y;
        reA[p1] = v.z; imA[p1] = v.w;
    }
    float *sre = reA, *sim = imA;
    fft512_r4<1>(sre, sim, reB, imB, tab, t);
    float4* o4 = (float4*)(g_bufB + (size_t)row * 256);
    int w0 = 128 + 2 * t;            // crop x: keep [128,384)
    int p0 = PADI(w0), p1 = PADI(w0 + 1);
    o4[t] = make_float4(sre[p0], sim[p0], sre[p1], sim[p1]);
}

// ---------------------------------------------------------------------------
// Coil reduction: out[a,h,w] = sum_c conj(mps[c,h,w]) * v[c,a,h,w].
// Reads bufB [ca][h][w]. Planar out: Re plane then Im plane.
// ---------------------------------------------------------------------------
__global__ void k_outred(const float* __restrict__ mr, const float* __restrict__ mi,
                         float* __restrict__ out, int outFloats) {
    int row = blockIdx.x;            // a*256 + h
    int a = row >> 8;
    int h = row & 255;
    int w = threadIdx.x;             // 0..255
    float ar = 0.f, ai = 0.f;
    #pragma unroll
    for (int c = 0; c < C_; ++c) {
        float2 v = g_bufB[(((size_t)(c * A_ + a) * 256 + h)) * 256 + w];
        size_t mIdx = ((size_t)c * 256 + h) * 256 + w;
        float br = mr[mIdx], bi = -mi[mIdx];   // conj(mps)
        ar += v.x * br - v.y * bi;
        ai += v.x * bi + v.y * br;
    }
    size_t p = ((size_t)a * 256 + h) * 256 + w;
    size_t reIdx = p, imIdx = 327680 + p;
    if (reIdx < (size_t)outFloats) out[reIdx] = ar;
    if (imIdx < (size_t)outFloats) out[imIdx] = ai;
}

// ---------------------------------------------------------------------------
extern "C" void kernel_launch(void* const* d_in, const int* in_sizes, int n_in,
                              void* d_out, int out_size, void* d_ws, size_t ws_size,
                              hipStream_t stream) {
    const float* xr = (const float*)d_in[0];
    const float* xi = (const float*)d_in[1];
    const float* mr = (const float*)d_in[2];
    const float* mi = (const float*)d_in[3];
    const float* kr = (const float*)d_in[4];
    const float* ki = (const float*)d_in[5];
    float* out = (float*)d_out;
    (void)d_ws; (void)ws_size; (void)n_in; (void)in_sizes;

    const float scale = 4.0f / 262144.0f;   // OVERSAMP^2/(Hp*Wp), ortho norms

    k_kernT2 <<<dim3(16, 16, 25), dim3(32, 8), 0, stream>>>(kr, ki, scale);
    k_fft1c  <<<RPG * 256, 128, 0, stream>>>(xr, xi, mr, mi);
    k_transA <<<dim3(16, 8, RPG), dim3(32, 8), 0, stream>>>();
    k_colfmc <<<C_ * 512, 128, 0, stream>>>();
    k_transB <<<dim3(8, 16, RPG), dim3(32, 8), 0, stream>>>();
    k_outifft<<<RPG * 256, 128, 0, stream>>>();
    k_outred <<<A_ * 256, 256, 0, stream>>>(mr, mi, out, out_size);
}

// Round 4
// 312.632 us; speedup vs baseline: 1.1340x; 1.0636x over previous
//
#include <hip/hip_runtime.h>
#include <cstddef>

#define PI_F 3.14159265358979323846f
#define A_  5
#define C_  12
#define RPG (C_ * A_)    // (coil,a) rows = 60

// ---------------------------------------------------------------------------
// Pipeline (R3: y-first FFT order -> kern used in NATIVE layout, no kernT;
// transposes eliminated via XCD-local scattered reads):
//   k_inT   : transpose x (5 planes) + mps (12 planes) -> g_xT/g_mT [.][x][y]
//   k_fft1c : modulate mpsT*xT + pad y + FFT along y -> g_bufA[ca][x][ky]
//   k_colfmc: per (coil,ky): scatter-read x-columns of bufA, pad x, 5 fwd
//             FFTs along x, mix with kern[m][ky][kx] (coalesced, scale
//             folded), 5 inv FFTs, crop x -> g_bufB[ca][ky][x]
//   k_outfr : per (a,x): scatter-read ky-columns of bufB for all 12 coils,
//             inv FFT along ky, crop y, conj(mpsT) reduce -> g_oT[a][x][y]
//   k_outT  : transpose g_oT -> planar out[a][y][x]
// ca = coil*A_ + a.  HBM total ~345 MB (was ~990 MB).
// ---------------------------------------------------------------------------
__device__ float2 g_bufA[RPG * 256 * 512];  //  63 MB
__device__ float2 g_bufB[RPG * 512 * 256];  //  63 MB
__device__ float2 g_xT[5  * 65536];         // 2.5 MB  x transposed [a][x][y]
__device__ float2 g_mT[12 * 65536];         // 6 MB    mps transposed [c][x][y]
__device__ float2 g_oT[5  * 65536];         // 2.5 MB  out pre-transpose [a][x][y]

// ---------------------------------------------------------------------------
// SoA LDS FFT with index padding (data) + PADT-padded twiddle table.
// R2 counters showed 12.8M bank conflicts/dispatch from tab reads (stage 1:
// e1 in {0,32,64,96} -> one bank pair, 4-way; stages 2/3 8-way). PADT(i) =
// i + (i>>3) spreads the power-of-2 strides across bank pairs.
// ---------------------------------------------------------------------------
#define NP 528
__device__ inline int PADI(int i) { return i + (i >> 5); }
__device__ inline int PADT(int i) { return i + (i >> 3); }   // tab: 256 -> 288

__device__ inline void build_tabP(float2* tab, int t) {
    #pragma unroll
    for (int q = 0; q < 2; ++q) {
        int k = t + q * 128;
        float s, c;
        __sincosf(-2.0f * PI_F * (float)k * (1.0f / 512.0f), &s, &c);
        tab[PADT(k)] = make_float2(c, s);
    }
}

template<int DIR>
__device__ inline float2 cmulw(float2 v, float2 w) {
    float cv = w.x, sv = (DIR < 0) ? w.y : -w.y;   // DIR=+1 -> conj(w)
    return make_float2(v.x * cv - v.y * sv, v.x * sv + v.y * cv);
}

// 512-pt FFT, 128 threads: 4 radix-4 stages + 1 radix-2 stage.
// Input in (Ar,Ai) [PADI layout], RESULT lands in (Br,Bi); both are scratch.
// Stage sequence A->B->A->B->A, r2: A->B.  Ends with __syncthreads().
template<int DIR>
__device__ void fft512(float* Ar, float* Ai, float* Br, float* Bi,
                       const float2* tab, int t) {
    float *srcR = Ar, *srcI = Ai, *dstR = Br, *dstI = Bi;
    int Ns = 1;
    #pragma unroll
    for (int s = 0; s < 4; ++s) {
        __syncthreads();
        int j = t;
        int m = j & (Ns - 1);
        int e1 = m << (7 - 2 * s);            // e1 in [0,128)
        float2 w1 = tab[PADT(e1)], w2 = tab[PADT(2 * e1)];
        float2 w3 = make_float2(w1.x * w2.x - w1.y * w2.y,
                                w1.x * w2.y + w1.y * w2.x);   // W^(3*e1)
        int i0 = PADI(j), i1 = PADI(j + 128), i2 = PADI(j + 256), i3 = PADI(j + 384);
        float2 v0 = make_float2(srcR[i0], srcI[i0]);
        float2 v1 = cmulw<DIR>(make_float2(srcR[i1], srcI[i1]), w1);
        float2 v2 = cmulw<DIR>(make_float2(srcR[i2], srcI[i2]), w2);
        float2 v3 = cmulw<DIR>(make_float2(srcR[i3], srcI[i3]), w3);
        float2 t0 = make_float2(v0.x + v2.x, v0.y + v2.y);
        float2 t1 = make_float2(v0.x - v2.x, v0.y - v2.y);
        float2 t2 = make_float2(v1.x + v3.x, v1.y + v3.y);
        float2 t3 = make_float2(v1.x - v3.x, v1.y - v3.y);
        float2 y0 = make_float2(t0.x + t2.x, t0.y + t2.y);
        float2 y2 = make_float2(t0.x - t2.x, t0.y - t2.y);
        float2 y1, y3;
        if (DIR < 0) {
            y1 = make_float2(t1.x + t3.y, t1.y - t3.x);
            y3 = make_float2(t1.x - t3.y, t1.y + t3.x);
        } else {
            y1 = make_float2(t1.x - t3.y, t1.y + t3.x);
            y3 = make_float2(t1.x + t3.y, t1.y - t3.x);
        }
        int idxD = ((j & ~(Ns - 1)) << 2) | m;
        int o0 = PADI(idxD), o1 = PADI(idxD + Ns);
        int o2 = PADI(idxD + 2 * Ns), o3 = PADI(idxD + 3 * Ns);
        dstR[o0] = y0.x; dstI[o0] = y0.y;
        dstR[o1] = y1.x; dstI[o1] = y1.y;
        dstR[o2] = y2.x; dstI[o2] = y2.y;
        dstR[o3] = y3.x; dstI[o3] = y3.y;
        float* tr = srcR; srcR = dstR; dstR = tr;
        float* ti = srcI; srcI = dstI; dstI = ti;
        Ns <<= 2;
    }
    __syncthreads();
    #pragma unroll
    for (int q = 0; q < 2; ++q) {
        int j = t + q * 128;                  // j in [0,256)
        float2 w = tab[PADT(j)];
        int i0 = PADI(j), i1 = PADI(j + 256);
        float2 v0 = make_float2(srcR[i0], srcI[i0]);
        float2 tw = cmulw<DIR>(make_float2(srcR[i1], srcI[i1]), w);
        dstR[i0] = v0.x + tw.x; dstI[i0] = v0.y + tw.y;
        dstR[i1] = v0.x - tw.x; dstI[i1] = v0.y - tw.y;
    }
    __syncthreads();
}

// ---------------------------------------------------------------------------
// Input transpose: x planes (z<5) and mps planes (z in [5,17)) -> [.][x][y]
// float2-interleaved. 17 * 256KB planes, ~17 MB total traffic.
// ---------------------------------------------------------------------------
__global__ void k_inT(const float* __restrict__ xr, const float* __restrict__ xi,
                      const float* __restrict__ mr, const float* __restrict__ mi) {
    __shared__ float tR[32][33], tI[32][33];
    int z = blockIdx.z;
    const float* pr; const float* pi; float2* dst;
    if (z < 5) {
        pr = xr + (size_t)z * 65536; pi = xi + (size_t)z * 65536;
        dst = g_xT + (size_t)z * 65536;
    } else {
        int c = z - 5;
        pr = mr + (size_t)c * 65536; pi = mi + (size_t)c * 65536;
        dst = g_mT + (size_t)c * 65536;
    }
    int w0 = blockIdx.x * 32, h0 = blockIdx.y * 32;
    int tx = threadIdx.x, ty = threadIdx.y;
    for (int i = ty; i < 32; i += 8) {
        size_t idx = (size_t)(h0 + i) * 256 + (w0 + tx);
        tR[i][tx] = pr[idx];
        tI[i][tx] = pi[idx];
    }
    __syncthreads();
    for (int i = ty; i < 32; i += 8)
        dst[(size_t)(w0 + i) * 256 + (h0 + tx)] =
            make_float2(tR[tx][i], tI[tx][i]);
}

// ---------------------------------------------------------------------------
// Pass 1: modulate mpsT*xT, pad y, FFT along y. Block = ca*256 + xcol.
// Writes g_bufA[ca][x][ky] rows (coalesced).
// ---------------------------------------------------------------------------
__global__ void k_fft1c() {
    int row = blockIdx.x;
    int ca = row >> 8;
    int xcol = row & 255;
    int coil = ca / A_;
    int a = ca - coil * A_;
    int t = threadIdx.x;
    __shared__ float Are[NP], Aim[NP], Bre[NP], Bim[NP];
    __shared__ float2 tab[288];
    build_tabP(tab, t);
    const float2* xs = g_xT + (size_t)a * 65536 + (size_t)xcol * 256;
    const float2* ms = g_mT + (size_t)coil * 65536 + (size_t)xcol * 256;
    // y-pad: slots [0,128) and [384,512) zero; data at y5 = y + 128
    Are[PADI(t)] = 0.f;       Aim[PADI(t)] = 0.f;
    Are[PADI(t + 384)] = 0.f; Aim[PADI(t + 384)] = 0.f;
    {
        float2 xv = xs[t], mv = ms[t];
        int p = PADI(t + 128);
        Are[p] = xv.x * mv.x - xv.y * mv.y;
        Aim[p] = xv.x * mv.y + xv.y * mv.x;
        xv = xs[t + 128]; mv = ms[t + 128];
        p = PADI(t + 256);
        Are[p] = xv.x * mv.x - xv.y * mv.y;
        Aim[p] = xv.x * mv.y + xv.y * mv.x;
    }
    fft512<-1>(Are, Aim, Bre, Bim, tab, t);
    float2* o = (float2*)g_bufA + (size_t)row * 512;
    #pragma unroll
    for (int q = 0; q < 4; ++q) {
        int k = t + q * 128;
        int p = PADI(k);
        o[k] = make_float2(Bre[p], Bim[p]);
    }
}

// ---------------------------------------------------------------------------
// FUSED pass 2: per (coil,ky): 5 fwd x-FFTs + mix + 5 inv x-FFTs.
//   - input scatter-read from bufA[ca][x][ky] (lane stride 4KB); every 64B
//     line covers 8 consecutive ky -> fully reused by the 8 ky-siblings of
//     this block's octet, which the swizzle pins to the same XCD. No transA.
//   - K read from ORIGINAL kr/ki [m][ky][kx]: lanes vary kx (fast axis) ->
//     coalesced; scale folded into mix; no kernT pass. K row (102 KB/ky)
//     reused by the 12 coil-blocks of this ky, same XCD.
//   - FFT result lands directly in FR/FI (ping-pong scratch<->FR): deletes
//     the 2x10 per-FFT LDS copy loops of R2.
//   - K loaded in register batches of 25 (50 loads in flight) per q.
// Swizzle: b -> xcd=b&7, s=b>>3; v=s/96, w=s%96; octet u=xcd+8v;
//          coil=w%12, ky=8u+w/12.  Bijective; octet u (12 coils x 8 ky = 96
//          blocks) all on XCD u%8 within a 768-id window.
// LDS: S 4.2K + FR/FI 21.1K + tab 2.3K = 27.7 KB -> 5 blocks/CU.
// ---------------------------------------------------------------------------
__global__ void __launch_bounds__(128) k_colfmc(const float* __restrict__ kr,
                                                const float* __restrict__ ki) {
    int b = blockIdx.x;
    int xcd = b & 7;
    int s = b >> 3;                  // 0..767
    int v = s / 96, w = s % 96;
    int u = xcd + (v << 3);          // ky-octet 0..63
    int coil = w % C_;
    int ky = (u << 3) + (w / C_);
    int t = threadIdx.x;
    __shared__ float Sre[NP], Sim[NP];
    __shared__ float FR[A_][NP], FI[A_][NP];
    __shared__ float2 tab[288];
    build_tabP(tab, t);

    // ---- forward: 5 ain x-FFTs, pad-on-load, scattered bufA reads ----
    for (int ain = 0; ain < A_; ++ain) {
        const float2* src = (const float2*)g_bufA +
                            ((size_t)(coil * A_ + ain) << 17);   // [x][ky]
        float2 v1 = src[(size_t)t * 512 + ky];          // x = t
        float2 v2 = src[(size_t)(t + 128) * 512 + ky];  // x = t+128
        Sre[PADI(t)] = 0.f;       Sim[PADI(t)] = 0.f;
        Sre[PADI(t + 384)] = 0.f; Sim[PADI(t + 384)] = 0.f;
        int p = PADI(t + 128);
        Sre[p] = v1.x; Sim[p] = v1.y;
        p = PADI(t + 256);
        Sre[p] = v2.x; Sim[p] = v2.y;
        fft512<-1>(Sre, Sim, FR[ain], FI[ain], tab, t);  // result -> FR/FI[ain]
    }

    // ---- mix: G[aout] = scale * sum_ain kern[aout][ain][ky][kx] * F[ain] ----
    const float scale = 4.0f / 262144.0f;   // OVERSAMP^2 / (Hp*Wp)
    size_t kyBase = (size_t)ky << 9;
    #pragma unroll
    for (int q = 0; q < 4; ++q) {
        int kx = t + q * 128;
        float krB[25], kiB[25];
        #pragma unroll
        for (int m = 0; m < 25; ++m) {
            size_t idx = ((size_t)m << 18) + kyBase + kx;
            krB[m] = kr[idx];
            kiB[m] = ki[idx];
        }
        int p = PADI(kx);
        float fr[A_], fi[A_];
        #pragma unroll
        for (int ain = 0; ain < A_; ++ain) {
            fr[ain] = FR[ain][p];
            fi[ain] = FI[ain][p];
        }
        #pragma unroll
        for (int aout = 0; aout < A_; ++aout) {
            float gr = 0.f, gi = 0.f;
            #pragma unroll
            for (int ain = 0; ain < A_; ++ain) {
                float kre = krB[aout * A_ + ain], kim = kiB[aout * A_ + ain];
                gr += kre * fr[ain] - kim * fi[ain];
                gi += kre * fi[ain] + kim * fr[ain];
            }
            FR[aout][p] = scale * gr;
            FI[aout][p] = scale * gi;
        }
    }
    // per-thread kx ownership -> no barrier needed; fft's head barrier covers

    // ---- inverse: 5 aout x-IFFTs, crop x, coalesced store to bufB ----
    for (int aout = 0; aout < A_; ++aout) {
        fft512<1>(FR[aout], FI[aout], Sre, Sim, tab, t);  // result -> S
        float4* o4 = (float4*)((float2*)g_bufB +
            ((size_t)(coil * A_ + aout) * 512 + ky) * 256);
        int x0 = 128 + 2 * t;        // keep x in [128,384)
        int p0 = PADI(x0), p1 = PADI(x0 + 1);
        o4[t] = make_float4(Sre[p0], Sim[p0], Sre[p1], Sim[p1]);
    }
}

// ---------------------------------------------------------------------------
// FUSED output: per (a,xcol): 12 coil ky-IFFTs + crop y + conj(mpsT) reduce.
//   - scatter-read bufB[ca][ky][x] (lane stride 2KB); 64B line = 8 x-values,
//     reused by the 8 xcol-siblings pinned to one XCD by the swizzle.
//   - mpsT float4 loads (contiguous y); accumulate in registers.
// Swizzle: b -> xcd=b&7, s=b>>3; v=s>>3, w=s&7; g=xcd+8v; a=g>>5,
//          xcol=((g&31)<<3)+w. Bijective over 1280 blocks.
// Writes g_oT[a][x][y] (coalesced float4); final transpose in k_outT.
// ---------------------------------------------------------------------------
__global__ void k_outfr() {
    int b = blockIdx.x;
    int xcd = b & 7;
    int s = b >> 3;                  // 0..159
    int v = s >> 3, w = s & 7;
    int g = xcd + (v << 3);          // 0..159
    int a = g >> 5;
    int xcol = ((g & 31) << 3) + w;
    int t = threadIdx.x;
    __shared__ float Are[NP], Aim[NP], Bre[NP], Bim[NP];
    __shared__ float2 tab[288];
    build_tabP(tab, t);
    float ar0 = 0.f, ai0 = 0.f, ar1 = 0.f, ai1 = 0.f;
    int y0 = 128 + 2 * t;            // crop y: keep [128,384)
    for (int c = 0; c < C_; ++c) {
        const float2* src = (const float2*)g_bufB +
                            ((size_t)(c * A_ + a) << 17);   // [ky][x]
        #pragma unroll
        for (int q = 0; q < 4; ++q) {
            int kyq = t + q * 128;
            float2 vv = src[(size_t)kyq * 256 + xcol];
            int p = PADI(kyq);
            Are[p] = vv.x; Aim[p] = vv.y;
        }
        fft512<1>(Are, Aim, Bre, Bim, tab, t);
        const float4* mp4 = (const float4*)(g_mT + (size_t)c * 65536 +
                                            (size_t)xcol * 256);
        float4 mm = mp4[t];          // mps at y = 2t (x,y), 2t+1 (z,w)
        int p0 = PADI(y0), p1 = PADI(y0 + 1);
        float v0x = Bre[p0], v0y = Bim[p0];
        float v1x = Bre[p1], v1y = Bim[p1];
        // acc += v * conj(m)
        ar0 += v0x * mm.x + v0y * mm.y;  ai0 += v0y * mm.x - v0x * mm.y;
        ar1 += v1x * mm.z + v1y * mm.w;  ai1 += v1y * mm.z - v1x * mm.w;
    }
    float4* o4 = (float4*)(g_oT + (size_t)a * 65536 + (size_t)xcol * 256);
    o4[t] = make_float4(ar0, ai0, ar1, ai1);
}

// ---------------------------------------------------------------------------
// Output transpose: g_oT[a][x][y] -> planar out[a][y][x] (Re plane, Im plane).
// ---------------------------------------------------------------------------
__global__ void k_outT(float* __restrict__ out, int outFloats) {
    __shared__ float tR[32][33], tI[32][33];
    int a = blockIdx.z;
    int x0 = blockIdx.x * 32, y0 = blockIdx.y * 32;
    const float2* src = g_oT + (size_t)a * 65536;
    int tx = threadIdx.x, ty = threadIdx.y;
    for (int i = ty; i < 32; i += 8) {
        float2 vv = src[(size_t)(x0 + i) * 256 + (y0 + tx)];
        tR[i][tx] = vv.x; tI[i][tx] = vv.y;
    }
    __syncthreads();
    for (int i = ty; i < 32; i += 8) {
        size_t reIdx = (size_t)a * 65536 + (size_t)(y0 + i) * 256 + (x0 + tx);
        size_t imIdx = 327680 + reIdx;
        if (reIdx < (size_t)outFloats) out[reIdx] = tR[tx][i];
        if (imIdx < (size_t)outFloats) out[imIdx] = tI[tx][i];
    }
}

// ---------------------------------------------------------------------------
extern "C" void kernel_launch(void* const* d_in, const int* in_sizes, int n_in,
                              void* d_out, int out_size, void* d_ws, size_t ws_size,
                              hipStream_t stream) {
    const float* xr = (const float*)d_in[0];
    const float* xi = (const float*)d_in[1];
    const float* mr = (const float*)d_in[2];
    const float* mi = (const float*)d_in[3];
    const float* kr = (const float*)d_in[4];
    const float* ki = (const float*)d_in[5];
    float* out = (float*)d_out;
    (void)d_ws; (void)ws_size; (void)n_in; (void)in_sizes;

    k_inT   <<<dim3(8, 8, 17), dim3(32, 8), 0, stream>>>(xr, xi, mr, mi);
    k_fft1c <<<RPG * 256, 128, 0, stream>>>();
    k_colfmc<<<C_ * 512, 128, 0, stream>>>(kr, ki);
    k_outfr <<<A_ * 256, 128, 0, stream>>>();
    k_outT  <<<dim3(8, 8, 5), dim3(32, 8), 0, stream>>>(out, out_size);
}